// Round 2
// baseline (2129.658 us; speedup 1.0000x reference)
//
#include <hip/hip_runtime.h>
#include <math.h>

#define BATCH 4096
#define HID   1024
#define KDIM  1024
#define NSTEP 15        // TIME_LIMIT - 1 scan steps

// GEMM v2: B from SGPRs (uniform s_load), A via LDS (1 conflict-free b32/k).
// Block: 256 threads = 4 waves. Tile: TM=128 rows x TN=64 cols, BK=32.
// Wave w: rows (w&1)*64, cols (w>>1)*32. Per-lane: 1 A-row, 32 acc.
#define TM 128
#define TN 64
#define BK 32

__global__ __launch_bounds__(256) void setup_kernel(const float* __restrict__ W_ih,
                                                    float* __restrict__ flagcol,
                                                    int* __restrict__ list0,
                                                    int* __restrict__ counts,
                                                    float* __restrict__ halt_accum,
                                                    float* __restrict__ tot_rem) {
    int i = blockIdx.x * 256 + threadIdx.x;   // grid 16 -> 4096 threads
    if (i < BATCH) { list0[i] = i; halt_accum[i] = 0.f; tot_rem[i] = 0.f; }
    if (i < 16) counts[i] = (i == 0) ? BATCH : 0;
    if (i < KDIM) flagcol[i] = W_ih[(size_t)i * 1025 + 1024];   // last col of W_ih
}

// Tiled 64x64 transpose: dst[c*1024 + r] = src[r*S + c].  Scalar reads (S may
// be 1025 -> rows unaligned for float4), coalesced float4 writes.
__global__ __launch_bounds__(256) void transpose_kernel(const float* __restrict__ src,
                                                        float* __restrict__ dst, int S) {
    __shared__ float T[64][65];
    int r0 = blockIdx.y * 64, c0 = blockIdx.x * 64;
    int t = threadIdx.x;
#pragma unroll
    for (int i = 0; i < 4; i++) {
        int s = t + i * 256;
        int r = s >> 4, c4 = (s & 15) * 4;
        const float* p = src + (size_t)(r0 + r) * S + c0 + c4;
#pragma unroll
        for (int j = 0; j < 4; j++) T[c4 + j][r] = p[j];
    }
    __syncthreads();
#pragma unroll
    for (int i = 0; i < 4; i++) {
        int s = t + i * 256;
        int c = s >> 4, r4 = (s & 15) * 4;
        float4 v = make_float4(T[c][r4], T[c][r4 + 1], T[c][r4 + 2], T[c][r4 + 3]);
        *(float4*)(dst + (size_t)(c0 + c) * 1024 + r0 + r4) = v;
    }
}

// mode 0: Cout[row] = A[row] @ B^T + bias                       (x_base)
// mode 1: Cout[row] = tanh(acc + xbase[row] + flag*flagcol + bias)  (step)
// Bt is k-major transposed weights: Bt[k][n] = W[n][k].
__global__ __launch_bounds__(256) void gemm_kernel(
    const float* __restrict__ A, const float* __restrict__ Bt,
    const float* __restrict__ bias,
    const float* __restrict__ xbase, const float* __restrict__ flagcol, float flag,
    const int* __restrict__ list, const int* __restrict__ pcount,
    float* __restrict__ Cout, int mode) {
    int count = pcount ? *pcount : BATCH;
    int row0 = blockIdx.x * TM;
    if (row0 >= count) return;
    int n0 = blockIdx.y * TN;

    __shared__ union {
        float a[BK][TM + 1];     // k-major A tile; stride 129 -> 2-way max on write
        float c[4][64 * 33];     // per-wave C transpose buffer
    } sm;

    int t = threadIdx.x;
    int lane = t & 63;
    int w = t >> 6;
    int wrow = (w & 1) * 64;
    int wcol = __builtin_amdgcn_readfirstlane((t >> 7) * 32);  // force SGPR

    // A staging: tile 128 rows x 8 float4 = 1024 quads; 4 per thread
    const float* aptr[4];
    int arow[4], akq[4];
#pragma unroll
    for (int i = 0; i < 4; i++) {
        int s = t + i * 256;
        int r = s >> 3, kq = s & 7;
        arow[i] = r; akq[i] = kq;
        int rr = row0 + r;
        int grow = 0;
        if (rr < count) grow = list ? list[rr] : rr;   // OOB rows read row 0
        aptr[i] = A + (size_t)grow * KDIM + kq * 4;
    }

    float acc[32];
#pragma unroll
    for (int n = 0; n < 32; n++) acc[n] = 0.f;

    for (int k0 = 0; k0 < KDIM; k0 += BK) {
        float4 av[4];
#pragma unroll
        for (int i = 0; i < 4; i++) av[i] = *(const float4*)(aptr[i] + k0);
        __syncthreads();
#pragma unroll
        for (int i = 0; i < 4; i++) {
            sm.a[akq[i] * 4 + 0][arow[i]] = av[i].x;
            sm.a[akq[i] * 4 + 1][arow[i]] = av[i].y;
            sm.a[akq[i] * 4 + 2][arow[i]] = av[i].z;
            sm.a[akq[i] * 4 + 3][arow[i]] = av[i].w;
        }
        __syncthreads();
#pragma unroll
        for (int k = 0; k < BK; k++) {
            float a = sm.a[k][wrow + lane];                      // conflict-free b32
            const float* bp = Bt + (size_t)(k0 + k) * KDIM + n0 + wcol;  // uniform
#pragma unroll
            for (int n = 0; n < 32; n += 4) {
                float4 bv = *(const float4*)(bp + n);            // -> s_load
                acc[n + 0] = fmaf(bv.x, a, acc[n + 0]);
                acc[n + 1] = fmaf(bv.y, a, acc[n + 1]);
                acc[n + 2] = fmaf(bv.z, a, acc[n + 2]);
                acc[n + 3] = fmaf(bv.w, a, acc[n + 3]);
            }
        }
    }

    // bias (uniform per column)
#pragma unroll
    for (int n = 0; n < 32; n += 4) {
        float4 bb = *(const float4*)(bias + n0 + wcol + n);
        acc[n + 0] += bb.x; acc[n + 1] += bb.y;
        acc[n + 2] += bb.z; acc[n + 3] += bb.w;
    }

    // per-wave LDS transpose for coalesced stores
    __syncthreads();                 // sm.a -> sm.c reuse
    float* cw = sm.c[w];             // 64 rows x 33 stride
#pragma unroll
    for (int n = 0; n < 32; n++) cw[lane * 33 + n] = acc[n];     // 2-way max

#pragma unroll
    for (int i = 0; i < 8; i++) {
        int r = i * 8 + (lane >> 3);
        int c0 = (lane & 7) * 4;
        int rr = row0 + wrow + r;
        if (rr >= count) continue;
        int grow = list ? list[rr] : rr;
        int col = n0 + wcol + c0;
        float4 v = make_float4(cw[r * 33 + c0], cw[r * 33 + c0 + 1],
                               cw[r * 33 + c0 + 2], cw[r * 33 + c0 + 3]);
        if (mode == 1) {
            float4 xb = *(const float4*)(xbase + (size_t)grow * KDIM + col);
            float4 fc = *(const float4*)(flagcol + col);
            v.x = tanhf(v.x + xb.x + flag * fc.x);
            v.y = tanhf(v.y + xb.y + flag * fc.y);
            v.z = tanhf(v.z + xb.z + flag * fc.z);
            v.w = tanhf(v.w + xb.w + flag * fc.w);
        }
        *(float4*)(Cout + (size_t)grow * KDIM + col) = v;        // coalesced 128B/8rows
    }
}

// One wave per active row: halt logit, sigmoid, halting state machine,
// tot_h accumulation into d_out, compaction of next-step list.
__global__ __launch_bounds__(256) void halt_kernel(
    const float* __restrict__ h, const float* __restrict__ W_halt,
    const float* __restrict__ b_halt,
    const int* __restrict__ list, const int* __restrict__ pcount,
    int* __restrict__ list_next, int* __restrict__ pcount_next,
    float* __restrict__ halt_accum, float* __restrict__ tot_rem,
    float* __restrict__ tot_h, float* __restrict__ steps_out,
    int stepnum, int first) {
    int count = *pcount;
    int wid = threadIdx.x >> 6, lane = threadIdx.x & 63;
    int r = blockIdx.x * 4 + wid;
    if (r >= count) return;
    int row = list[r];
    const float* hr = h + (size_t)row * HID;

    float dot = 0.f;
#pragma unroll
    for (int q = 0; q < 4; q++) {
        int c = q * 256 + lane * 4;
        float4 hv = *(const float4*)(hr + c);
        float4 wv = *(const float4*)(W_halt + c);
        dot += hv.x * wv.x + hv.y * wv.y + hv.z * wv.z + hv.w * wv.w;
    }
#pragma unroll
    for (int off = 32; off > 0; off >>= 1) dot += __shfl_down(dot, off);

    float combined = 0.f;
    if (lane == 0) {
        float p = 1.f / (1.f + expf(-(dot + b_halt[0])));
        float S = halt_accum[row] + p;
        halt_accum[row] = S;
        tot_rem[row] += p;
        bool ending = (S + p) > 0.99f;      // budget = 1 - PONDER_EPS
        if (ending) {
            combined = p + (1.f - S);
            steps_out[row] = (float)stepnum;
        } else {
            combined = p;
            int idx = atomicAdd(pcount_next, 1);
            list_next[idx] = row;
        }
    }
    combined = __shfl(combined, 0);

    float* th = tot_h + (size_t)row * HID;
#pragma unroll
    for (int q = 0; q < 4; q++) {
        int c = q * 256 + lane * 4;
        float4 hv = *(const float4*)(hr + c);
        float4 ov;
        if (first) {
            ov.x = combined * hv.x; ov.y = combined * hv.y;
            ov.z = combined * hv.z; ov.w = combined * hv.w;
        } else {
            ov = *(const float4*)(th + c);
            ov.x += combined * hv.x; ov.y += combined * hv.y;
            ov.z += combined * hv.z; ov.w += combined * hv.w;
        }
        *(float4*)(th + c) = ov;
    }
}

// Survivors after all 15 steps: tot_h += (1 - halt_accum) * h_final; steps = 16
__global__ __launch_bounds__(256) void epilogue_kernel(
    const float* __restrict__ h, const int* __restrict__ list,
    const int* __restrict__ pcount, const float* __restrict__ halt_accum,
    float* __restrict__ tot_h, float* __restrict__ steps_out) {
    int count = *pcount;
    int wid = threadIdx.x >> 6, lane = threadIdx.x & 63;
    int r = blockIdx.x * 4 + wid;
    if (r >= count) return;
    int row = list[r];
    float cmb = 1.f - halt_accum[row];
    if (lane == 0) steps_out[row] = 16.f;
    const float* hr = h + (size_t)row * HID;
    float* th = tot_h + (size_t)row * HID;
#pragma unroll
    for (int q = 0; q < 4; q++) {
        int c = q * 256 + lane * 4;
        float4 hv = *(const float4*)(hr + c);
        float4 ov = *(const float4*)(th + c);
        ov.x += cmb * hv.x; ov.y += cmb * hv.y;
        ov.z += cmb * hv.z; ov.w += cmb * hv.w;
        *(float4*)(th + c) = ov;
    }
}

__global__ __launch_bounds__(256) void ponder_kernel(const float* __restrict__ tot_rem,
                                                     float* __restrict__ out) {
    __shared__ float s[4];
    float v = 0.f;
#pragma unroll
    for (int i = 0; i < 16; i++) v += tot_rem[threadIdx.x + i * 256];
#pragma unroll
    for (int off = 32; off > 0; off >>= 1) v += __shfl_down(v, off);
    int lane = threadIdx.x & 63, wid = threadIdx.x >> 6;
    if (lane == 0) s[wid] = v;
    __syncthreads();
    if (threadIdx.x == 0) out[0] = (s[0] + s[1] + s[2] + s[3]) * (-0.01f / 4096.f);
}

extern "C" void kernel_launch(void* const* d_in, const int* in_sizes, int n_in,
                              void* d_out, int out_size, void* d_ws, size_t ws_size,
                              hipStream_t stream) {
    const float* inputs = (const float*)d_in[0];
    const float* hidden = (const float*)d_in[1];
    const float* W_ih   = (const float*)d_in[2];
    const float* b_ih   = (const float*)d_in[3];
    const float* W_hh   = (const float*)d_in[4];
    const float* b_hh   = (const float*)d_in[5];
    const float* W_halt = (const float*)d_in[6];
    const float* b_halt = (const float*)d_in[7];
    float* out = (float*)d_out;

    float* ws = (float*)d_ws;
    float* xbase = ws;                                   // 4096*1024
    float* h0 = xbase + (size_t)BATCH * HID;             // 4096*1024
    float* h1 = h0 + (size_t)BATCH * HID;                // 4096*1024 (BtA早期, h from t=1)
    float* BtH = h1 + (size_t)BATCH * HID;               // 1024*1024 W_hh^T (k-major)
    float* flagcol = BtH + (size_t)KDIM * KDIM;          // 1024
    float* halt_accum = flagcol + KDIM;                  // 4096
    float* tot_rem = halt_accum + BATCH;                 // 4096
    int* list0 = (int*)(tot_rem + BATCH);                // 4096 ints
    int* list1 = list0 + BATCH;                          // 4096 ints
    int* counts = list1 + BATCH;                         // 16 ints

    float* BtA = h1;   // W_ih^T lives in h1's space; dead before t=1 writes h1

    float* hb[2] = {h0, h1};
    int* lists[2] = {list0, list1};

    float* tot_h = out;                                  // 4096*1024
    float* ponder = out + (size_t)BATCH * HID;           // 1
    float* steps_out = ponder + 1;                       // 4096

    setup_kernel<<<16, 256, 0, stream>>>(W_ih, flagcol, list0, counts, halt_accum, tot_rem);
    transpose_kernel<<<dim3(16, 16), 256, 0, stream>>>(W_ih, BtA, 1025);
    transpose_kernel<<<dim3(16, 16), 256, 0, stream>>>(W_hh, BtH, 1024);

    // x_base = inputs @ W_ih[:, :-1].T + b_ih
    gemm_kernel<<<dim3(32, 16), 256, 0, stream>>>(inputs, BtA, b_ih, nullptr, nullptr, 0.f,
                                                  nullptr, nullptr, xbase, 0);
    for (int t = 0; t < NSTEP; t++) {
        const float* hprev = (t == 0) ? hidden : hb[(t - 1) & 1];
        gemm_kernel<<<dim3(32, 16), 256, 0, stream>>>(hprev, BtH, b_hh, xbase, flagcol,
                                                      (t == 0) ? 1.f : 0.f,
                                                      lists[t & 1], counts + t, hb[t & 1], 1);
        halt_kernel<<<1024, 256, 0, stream>>>(hb[t & 1], W_halt, b_halt,
                                              lists[t & 1], counts + t,
                                              lists[(t + 1) & 1], counts + t + 1,
                                              halt_accum, tot_rem, tot_h, steps_out,
                                              t + 1, (t == 0) ? 1 : 0);
    }
    epilogue_kernel<<<1024, 256, 0, stream>>>(hb[0], lists[1], counts + 15,
                                              halt_accum, tot_h, steps_out);
    ponder_kernel<<<1, 256, 0, stream>>>(tot_rem, ponder);
}

// Round 3
// 2104.244 us; speedup vs baseline: 1.0121x; 1.0121x over previous
//
#include <hip/hip_runtime.h>
#include <hip/hip_cooperative_groups.h>
#include <math.h>

namespace cg = cooperative_groups;

#define BATCH 4096
#define HID   1024
#define KDIM  1024
#define NSTEP 15        // TIME_LIMIT - 1 scan steps
#define GRID  512       // 2 blocks/CU, co-resident (cooperative)

// GEMM tiling (R1 core): C-tile 128x64, BK=16, 256 threads, 8x4 microtile
#define TM 128
#define TN 64
#define BK 16
#define LDA (TM + 4)
#define LDB (TN + 4)

// mode 0: Cout[row] = A[row] @ B^T + bias               (x_base)
// mode 1: Cout[row] = tanh(acc + xbase[row] + flag*flagcol + bias)
__device__ __forceinline__ void gemm_tile(
    float As[BK][LDA], float Bs[BK][LDB],
    const float* __restrict__ A, const float* __restrict__ B,
    const float* __restrict__ bias,
    const float* __restrict__ xbase, const float* __restrict__ flagcol, float flag,
    const int* __restrict__ list, int count,
    float* __restrict__ Cout, int mode, int row0, int col0) {
    int t = threadIdx.x;
    int tx = t & 15, ty = t >> 4;

    // A-tile staging: 128 rows x 4 float4-cols = 512 slots, 2 per thread
    const float* aptr[2];
    int arow[2], akq[2];
#pragma unroll
    for (int l = 0; l < 2; l++) {
        int s = t + l * 256;
        int r = s >> 2, kq = s & 3;
        arow[l] = r; akq[l] = kq;
        int rr = row0 + r;
        int grow = 0;
        if (rr < count) grow = list ? list[rr] : rr;   // OOB rows read row 0 (never stored)
        aptr[l] = A + (size_t)grow * KDIM + kq * 4;
    }
    // B-tile staging: 64 rows x 4 float4-cols = 256 slots, 1 per thread
    int brow = t >> 2, bkq = t & 3;
    const float* bptr = B + (size_t)(col0 + brow) * KDIM + bkq * 4;

    float acc[8][4];
#pragma unroll
    for (int i = 0; i < 8; i++)
#pragma unroll
        for (int j = 0; j < 4; j++) acc[i][j] = 0.f;

    for (int k0 = 0; k0 < KDIM; k0 += BK) {
        float4 av0 = *(const float4*)(aptr[0] + k0);
        float4 av1 = *(const float4*)(aptr[1] + k0);
        float4 bv  = *(const float4*)(bptr + k0);
        __syncthreads();
        As[akq[0] * 4 + 0][arow[0]] = av0.x;
        As[akq[0] * 4 + 1][arow[0]] = av0.y;
        As[akq[0] * 4 + 2][arow[0]] = av0.z;
        As[akq[0] * 4 + 3][arow[0]] = av0.w;
        As[akq[1] * 4 + 0][arow[1]] = av1.x;
        As[akq[1] * 4 + 1][arow[1]] = av1.y;
        As[akq[1] * 4 + 2][arow[1]] = av1.z;
        As[akq[1] * 4 + 3][arow[1]] = av1.w;
        Bs[bkq * 4 + 0][brow] = bv.x;
        Bs[bkq * 4 + 1][brow] = bv.y;
        Bs[bkq * 4 + 2][brow] = bv.z;
        Bs[bkq * 4 + 3][brow] = bv.w;
        __syncthreads();
#pragma unroll
        for (int k = 0; k < BK; k++) {
            float4 a0 = *(const float4*)&As[k][ty * 8];
            float4 a1 = *(const float4*)&As[k][ty * 8 + 4];
            float4 b0 = *(const float4*)&Bs[k][tx * 4];
            float a[8] = {a0.x, a0.y, a0.z, a0.w, a1.x, a1.y, a1.z, a1.w};
            float bb[4] = {b0.x, b0.y, b0.z, b0.w};
#pragma unroll
            for (int i = 0; i < 8; i++)
#pragma unroll
                for (int j = 0; j < 4; j++)
                    acc[i][j] = fmaf(a[i], bb[j], acc[i][j]);
        }
    }

#pragma unroll
    for (int i = 0; i < 8; i++) {
        int rr = row0 + ty * 8 + i;
        if (rr >= count) continue;
        int grow = list ? list[rr] : rr;
        int col = col0 + tx * 4;
        float4 bv = *(const float4*)(bias + col);
        float4 res;
        if (mode == 0) {
            res.x = acc[i][0] + bv.x;
            res.y = acc[i][1] + bv.y;
            res.z = acc[i][2] + bv.z;
            res.w = acc[i][3] + bv.w;
        } else {
            float4 xb = *(const float4*)(xbase + (size_t)grow * KDIM + col);
            float4 fc = *(const float4*)(flagcol + col);
            res.x = tanhf(acc[i][0] + xb.x + flag * fc.x + bv.x);
            res.y = tanhf(acc[i][1] + xb.y + flag * fc.y + bv.y);
            res.z = tanhf(acc[i][2] + xb.z + flag * fc.z + bv.z);
            res.w = tanhf(acc[i][3] + xb.w + flag * fc.w + bv.w);
        }
        *(float4*)(Cout + (size_t)grow * KDIM + col) = res;
    }
}

__global__ __launch_bounds__(256) void act_kernel(
    const float* __restrict__ inputs, const float* __restrict__ hidden,
    const float* __restrict__ W_ih, const float* __restrict__ b_ih,
    const float* __restrict__ W_hh, const float* __restrict__ b_hh,
    const float* __restrict__ W_halt, const float* __restrict__ b_halt,
    float* __restrict__ out, float* __restrict__ ws) {
    cg::grid_group gg = cg::this_grid();

    __shared__ float As[BK][LDA];
    __shared__ float Bs[BK][LDB];
    __shared__ float red[4];

    // workspace carve-up
    float* xbase = ws;                                   // 4096*1024
    float* h0 = xbase + (size_t)BATCH * HID;
    float* h1 = h0 + (size_t)BATCH * HID;
    float* Wp = h1 + (size_t)BATCH * HID;                // repacked W_ih (1024x1024)
    float* flagcol = Wp + (size_t)KDIM * KDIM;           // 1024
    float* halt_accum = flagcol + KDIM;                  // 4096
    float* tot_rem = halt_accum + BATCH;                 // 4096
    int* list0 = (int*)(tot_rem + BATCH);                // 4096
    int* list1 = list0 + BATCH;                          // 4096
    int* counts = list1 + BATCH;                         // 16

    float* tot_h = out;
    float* ponder = out + (size_t)BATCH * HID;
    float* steps_out = ponder + 1;

    int b = blockIdx.x, t = threadIdx.x;
    int gid = b * 256 + t;
    int lane = t & 63, wid = t >> 6;
    int gwave = b * 4 + wid;                             // 2048 waves total

    // ---- phase 0: init + repack W_ih ----
    for (int idx = gid; idx < KDIM * KDIM; idx += GRID * 256)
        Wp[idx] = W_ih[(size_t)(idx >> 10) * 1025 + (idx & 1023)];
    if (gid < BATCH) { list0[gid] = gid; halt_accum[gid] = 0.f; tot_rem[gid] = 0.f; }
    if (gid < KDIM) flagcol[gid] = W_ih[(size_t)gid * 1025 + 1024];
    if (gid < 16) counts[gid] = (gid == 0) ? BATCH : 0;
    gg.sync();

    // ---- phase 1: x_base = inputs @ W_ih[:, :-1].T + b_ih ----
    {
        int rowt = b & 31, colt = b >> 5;                // 32 x 16 = 512 tiles
        gemm_tile(As, Bs, inputs, Wp, b_ih, nullptr, nullptr, 0.f,
                  nullptr, BATCH, xbase, 0, rowt * TM, colt * TN);
    }
    gg.sync();

    float* hb[2] = {h0, h1};
    int* lists[2] = {list0, list1};

    int step = 0;
    for (; step < NSTEP; step++) {
        int count = ((volatile int*)counts)[step];
        if (count == 0) break;                            // uniform across grid
        const float* hprev = (step == 0) ? hidden : hb[(step - 1) & 1];
        const int* lst = lists[step & 1];
        float* hcur = hb[step & 1];
        int rowtiles = (count + TM - 1) / TM;
        int tiles = rowtiles * 16;                        // <= 512 == GRID
        if (b < tiles) {
            int rowt = b % rowtiles, colt = b / rowtiles;
            gemm_tile(As, Bs, hprev, W_hh, b_hh, xbase, flagcol,
                      (step == 0) ? 1.f : 0.f, lst, count, hcur, 1,
                      rowt * TM, colt * TN);
        }
        gg.sync();

        // ---- halt phase: 1 wave per active row ----
        int* lnext = lists[(step + 1) & 1];
        int* cnext = counts + step + 1;
        for (int r = gwave; r < count; r += GRID * 4) {
            int row = lst[r];
            const float* hr = hcur + (size_t)row * HID;
            float dot = 0.f;
#pragma unroll
            for (int q = 0; q < 4; q++) {
                int c = q * 256 + lane * 4;
                float4 hv = *(const float4*)(hr + c);
                float4 wv = *(const float4*)(W_halt + c);
                dot += hv.x * wv.x + hv.y * wv.y + hv.z * wv.z + hv.w * wv.w;
            }
#pragma unroll
            for (int off = 32; off > 0; off >>= 1) dot += __shfl_down(dot, off);

            float combined = 0.f;
            if (lane == 0) {
                float p = 1.f / (1.f + expf(-(dot + b_halt[0])));
                float S = halt_accum[row] + p;
                halt_accum[row] = S;
                tot_rem[row] += p;
                bool ending = (S + p) > 0.99f;            // budget = 1 - PONDER_EPS
                if (ending) {
                    combined = p + (1.f - S);
                    steps_out[row] = (float)(step + 1);
                } else {
                    combined = p;
                    int idx = atomicAdd(cnext, 1);
                    lnext[idx] = row;
                }
            }
            combined = __shfl(combined, 0);

            float* th = tot_h + (size_t)row * HID;
#pragma unroll
            for (int q = 0; q < 4; q++) {
                int c = q * 256 + lane * 4;
                float4 hv = *(const float4*)(hr + c);
                float4 ov;
                if (step == 0) {
                    ov.x = combined * hv.x; ov.y = combined * hv.y;
                    ov.z = combined * hv.z; ov.w = combined * hv.w;
                } else {
                    ov = *(const float4*)(th + c);
                    ov.x += combined * hv.x; ov.y += combined * hv.y;
                    ov.z += combined * hv.z; ov.w += combined * hv.w;
                }
                *(float4*)(th + c) = ov;
            }
        }
        gg.sync();
    }

    // ---- epilogue: survivors get (1 - halt_accum) * h_last, steps = 16 ----
    {
        int count = ((volatile int*)counts)[step];
        if (count > 0) {
            const float* hlast = hb[(step - 1) & 1];     // step >= 1 always here
            const int* lst = lists[step & 1];
            for (int r = gwave; r < count; r += GRID * 4) {
                int row = lst[r];
                float cmb = 1.f - halt_accum[row];
                if (lane == 0) steps_out[row] = 16.f;
                const float* hr = hlast + (size_t)row * HID;
                float* th = tot_h + (size_t)row * HID;
#pragma unroll
                for (int q = 0; q < 4; q++) {
                    int c = q * 256 + lane * 4;
                    float4 hv = *(const float4*)(hr + c);
                    float4 ov = *(const float4*)(th + c);
                    ov.x += cmb * hv.x; ov.y += cmb * hv.y;
                    ov.z += cmb * hv.z; ov.w += cmb * hv.w;
                    *(float4*)(th + c) = ov;
                }
            }
        }
        // ---- ponder: block 0 reduces tot_rem (complete since last halt sync) ----
        if (b == 0) {
            float v = 0.f;
#pragma unroll
            for (int i = 0; i < 16; i++) v += tot_rem[t + i * 256];
#pragma unroll
            for (int off = 32; off > 0; off >>= 1) v += __shfl_down(v, off);
            if (lane == 0) red[wid] = v;
            __syncthreads();
            if (t == 0) ponder[0] = (red[0] + red[1] + red[2] + red[3]) * (-0.01f / 4096.f);
        }
    }
}

extern "C" void kernel_launch(void* const* d_in, const int* in_sizes, int n_in,
                              void* d_out, int out_size, void* d_ws, size_t ws_size,
                              hipStream_t stream) {
    const float* inputs = (const float*)d_in[0];
    const float* hidden = (const float*)d_in[1];
    const float* W_ih   = (const float*)d_in[2];
    const float* b_ih   = (const float*)d_in[3];
    const float* W_hh   = (const float*)d_in[4];
    const float* b_hh   = (const float*)d_in[5];
    const float* W_halt = (const float*)d_in[6];
    const float* b_halt = (const float*)d_in[7];
    float* out = (float*)d_out;
    float* ws  = (float*)d_ws;

    void* args[] = {(void*)&inputs, (void*)&hidden, (void*)&W_ih, (void*)&b_ih,
                    (void*)&W_hh, (void*)&b_hh, (void*)&W_halt, (void*)&b_halt,
                    (void*)&out, (void*)&ws};
    hipLaunchCooperativeKernel((void*)act_kernel, dim3(GRID), dim3(256), args, 0, stream);
}

// Round 4
// 1819.226 us; speedup vs baseline: 1.1706x; 1.1567x over previous
//
#include <hip/hip_runtime.h>
#include <math.h>

#define BATCH 4096
#define HID   1024
#define KDIM  1024
#define NSTEP 15        // TIME_LIMIT - 1 scan steps

// GEMM v3: 128 threads (2 waves), C-tile TM=64 x TN=128, BK=16, 8x8 microtile.
// Rows {ty*4+i, 32+ty*4+i}, cols {tx*4+j, 64+tx*4+j}: all LDS reads are
// conflict-free or 2-way (free); 1.0 FMA per LDS byte (1.5x over 8x4 tile).
#define TM 64
#define TN 128
#define BK 16
#define LDA (TM + 4)     // 68: k-major A plane; stride%32=4 -> 2-way max on rw
#define LDB (TN + 4)     // 132

// init lists/accums + repack W_ih (stride 1025 -> 1024) + extract flag column
__global__ __launch_bounds__(256) void setup_kernel(const float* __restrict__ W_ih,
                                                    float* __restrict__ Wp,
                                                    float* __restrict__ flagcol,
                                                    int* __restrict__ list0,
                                                    int* __restrict__ counts,
                                                    float* __restrict__ halt_accum,
                                                    float* __restrict__ tot_rem) {
    int idx = blockIdx.x * 256 + threadIdx.x;           // grid 4096 -> 1M threads
    Wp[idx] = W_ih[(size_t)(idx >> 10) * 1025 + (idx & 1023)];
    if (idx < BATCH) { list0[idx] = idx; halt_accum[idx] = 0.f; tot_rem[idx] = 0.f; }
    if (idx < KDIM) flagcol[idx] = W_ih[(size_t)idx * 1025 + 1024];
    if (idx < 16) counts[idx] = (idx == 0) ? BATCH : 0;
}

// mode 0: Cout[row] = A[row] @ B^T + bias                       (x_base)
// mode 1: Cout[row] = tanh(acc + xbase[row] + flag*flagcol + bias)  (step)
__global__ __launch_bounds__(128) void gemm_kernel(
    const float* __restrict__ A, const float* __restrict__ B,
    const float* __restrict__ bias,
    const float* __restrict__ xbase, const float* __restrict__ flagcol, float flag,
    const int* __restrict__ list, const int* __restrict__ pcount,
    float* __restrict__ Cout, int mode) {
    int count = pcount ? *pcount : BATCH;
    int row0 = blockIdx.x * TM;
    if (row0 >= count) return;
    int col0 = blockIdx.y * TN;

    __shared__ float As[BK][LDA];
    __shared__ float Bs[BK][LDB];

    int t = threadIdx.x;
    int tx = t & 15, ty = t >> 4;

    // A staging: 64 rows x 4 kq = 256 quads, 2/thread
    const float* aptr[2];
    int arow[2], akq[2];
#pragma unroll
    for (int l = 0; l < 2; l++) {
        int s = t + l * 128;
        int r = s >> 2, kq = s & 3;
        arow[l] = r; akq[l] = kq;
        int rr = row0 + r;
        int grow = 0;
        if (rr < count) grow = list ? list[rr] : rr;   // OOB rows read row 0 (never stored)
        aptr[l] = A + (size_t)grow * KDIM + kq * 4;
    }
    // B staging: 128 n-rows x 4 kq = 512 quads, 4/thread
    const float* bptr[4];
    int bn[4], bkq[4];
#pragma unroll
    for (int l = 0; l < 4; l++) {
        int s = t + l * 128;
        int n = s >> 2, kq = s & 3;
        bn[l] = n; bkq[l] = kq;
        bptr[l] = B + (size_t)(col0 + n) * KDIM + kq * 4;
    }

    float acc[8][8];
#pragma unroll
    for (int i = 0; i < 8; i++)
#pragma unroll
        for (int j = 0; j < 8; j++) acc[i][j] = 0.f;

    for (int k0 = 0; k0 < KDIM; k0 += BK) {
        float4 av[2], bv[4];
#pragma unroll
        for (int l = 0; l < 2; l++) av[l] = *(const float4*)(aptr[l] + k0);
#pragma unroll
        for (int l = 0; l < 4; l++) bv[l] = *(const float4*)(bptr[l] + k0);
        __syncthreads();
#pragma unroll
        for (int l = 0; l < 2; l++) {
            As[akq[l] * 4 + 0][arow[l]] = av[l].x;
            As[akq[l] * 4 + 1][arow[l]] = av[l].y;
            As[akq[l] * 4 + 2][arow[l]] = av[l].z;
            As[akq[l] * 4 + 3][arow[l]] = av[l].w;
        }
#pragma unroll
        for (int l = 0; l < 4; l++) {
            Bs[bkq[l] * 4 + 0][bn[l]] = bv[l].x;
            Bs[bkq[l] * 4 + 1][bn[l]] = bv[l].y;
            Bs[bkq[l] * 4 + 2][bn[l]] = bv[l].z;
            Bs[bkq[l] * 4 + 3][bn[l]] = bv[l].w;
        }
        __syncthreads();
#pragma unroll
        for (int k = 0; k < BK; k++) {
            float4 a0 = *(const float4*)&As[k][ty * 4];
            float4 a1 = *(const float4*)&As[k][32 + ty * 4];
            float4 b0 = *(const float4*)&Bs[k][tx * 4];
            float4 b1 = *(const float4*)&Bs[k][64 + tx * 4];
            float a[8] = {a0.x, a0.y, a0.z, a0.w, a1.x, a1.y, a1.z, a1.w};
            float bb[8] = {b0.x, b0.y, b0.z, b0.w, b1.x, b1.y, b1.z, b1.w};
#pragma unroll
            for (int i = 0; i < 8; i++)
#pragma unroll
                for (int j = 0; j < 8; j++)
                    acc[i][j] = fmaf(a[i], bb[j], acc[i][j]);
        }
    }

    float4 bia0 = *(const float4*)(bias + col0 + tx * 4);
    float4 bia1 = *(const float4*)(bias + col0 + 64 + tx * 4);
    float4 fc0, fc1;
    if (mode == 1) {
        fc0 = *(const float4*)(flagcol + col0 + tx * 4);
        fc1 = *(const float4*)(flagcol + col0 + 64 + tx * 4);
    }
#pragma unroll
    for (int i = 0; i < 8; i++) {
        int r = (i < 4) ? (ty * 4 + i) : (32 + ty * 4 + i - 4);
        int rr = row0 + r;
        if (rr >= count) continue;
        int grow = list ? list[rr] : rr;
        float* crow = Cout + (size_t)grow * KDIM + col0;
        float4 v0 = make_float4(acc[i][0] + bia0.x, acc[i][1] + bia0.y,
                                acc[i][2] + bia0.z, acc[i][3] + bia0.w);
        float4 v1 = make_float4(acc[i][4] + bia1.x, acc[i][5] + bia1.y,
                                acc[i][6] + bia1.z, acc[i][7] + bia1.w);
        if (mode == 1) {
            const float* xr = xbase + (size_t)grow * KDIM + col0;
            float4 x0 = *(const float4*)(xr + tx * 4);
            float4 x1 = *(const float4*)(xr + 64 + tx * 4);
            v0.x = tanhf(v0.x + x0.x + flag * fc0.x);
            v0.y = tanhf(v0.y + x0.y + flag * fc0.y);
            v0.z = tanhf(v0.z + x0.z + flag * fc0.z);
            v0.w = tanhf(v0.w + x0.w + flag * fc0.w);
            v1.x = tanhf(v1.x + x1.x + flag * fc1.x);
            v1.y = tanhf(v1.y + x1.y + flag * fc1.y);
            v1.z = tanhf(v1.z + x1.z + flag * fc1.z);
            v1.w = tanhf(v1.w + x1.w + flag * fc1.w);
        }
        *(float4*)(crow + tx * 4) = v0;
        *(float4*)(crow + 64 + tx * 4) = v1;
    }
}

// One wave per active row: halt logit, sigmoid, halting state machine,
// tot_h accumulation into d_out, compaction of next-step list.
__global__ __launch_bounds__(256) void halt_kernel(
    const float* __restrict__ h, const float* __restrict__ W_halt,
    const float* __restrict__ b_halt,
    const int* __restrict__ list, const int* __restrict__ pcount,
    int* __restrict__ list_next, int* __restrict__ pcount_next,
    float* __restrict__ halt_accum, float* __restrict__ tot_rem,
    float* __restrict__ tot_h, float* __restrict__ steps_out,
    int stepnum, int first) {
    int count = *pcount;
    int wid = threadIdx.x >> 6, lane = threadIdx.x & 63;
    int r = blockIdx.x * 4 + wid;
    if (r >= count) return;
    int row = list[r];
    const float* hr = h + (size_t)row * HID;

    float dot = 0.f;
#pragma unroll
    for (int q = 0; q < 4; q++) {
        int c = q * 256 + lane * 4;
        float4 hv = *(const float4*)(hr + c);
        float4 wv = *(const float4*)(W_halt + c);
        dot += hv.x * wv.x + hv.y * wv.y + hv.z * wv.z + hv.w * wv.w;
    }
#pragma unroll
    for (int off = 32; off > 0; off >>= 1) dot += __shfl_down(dot, off);

    float combined = 0.f;
    if (lane == 0) {
        float p = 1.f / (1.f + expf(-(dot + b_halt[0])));
        float S = halt_accum[row] + p;
        halt_accum[row] = S;
        tot_rem[row] += p;
        bool ending = (S + p) > 0.99f;      // budget = 1 - PONDER_EPS
        if (ending) {
            combined = p + (1.f - S);
            steps_out[row] = (float)stepnum;
        } else {
            combined = p;
            int idx = atomicAdd(pcount_next, 1);
            list_next[idx] = row;
        }
    }
    combined = __shfl(combined, 0);

    float* th = tot_h + (size_t)row * HID;
#pragma unroll
    for (int q = 0; q < 4; q++) {
        int c = q * 256 + lane * 4;
        float4 hv = *(const float4*)(hr + c);
        float4 ov;
        if (first) {
            ov.x = combined * hv.x; ov.y = combined * hv.y;
            ov.z = combined * hv.z; ov.w = combined * hv.w;
        } else {
            ov = *(const float4*)(th + c);
            ov.x += combined * hv.x; ov.y += combined * hv.y;
            ov.z += combined * hv.z; ov.w += combined * hv.w;
        }
        *(float4*)(th + c) = ov;
    }
}

// blocks 0..1023: survivors get (1 - halt_accum) * h_final, steps = 16.
// block 1024: ponder reduction (tot_rem final since last halt_kernel).
__global__ __launch_bounds__(256) void epilogue_kernel(
    const float* __restrict__ h, const int* __restrict__ list,
    const int* __restrict__ pcount, const float* __restrict__ halt_accum,
    const float* __restrict__ tot_rem,
    float* __restrict__ tot_h, float* __restrict__ steps_out,
    float* __restrict__ ponder) {
    if (blockIdx.x == 1024) {
        __shared__ float red[4];
        int t = threadIdx.x;
        float v = 0.f;
#pragma unroll
        for (int i = 0; i < 16; i++) v += tot_rem[t + i * 256];
#pragma unroll
        for (int off = 32; off > 0; off >>= 1) v += __shfl_down(v, off);
        int lane = t & 63, wid = t >> 6;
        if (lane == 0) red[wid] = v;
        __syncthreads();
        if (t == 0) ponder[0] = (red[0] + red[1] + red[2] + red[3]) * (-0.01f / 4096.f);
        return;
    }
    int count = *pcount;
    int wid = threadIdx.x >> 6, lane = threadIdx.x & 63;
    int r = blockIdx.x * 4 + wid;
    if (r >= count) return;
    int row = list[r];
    float cmb = 1.f - halt_accum[row];
    if (lane == 0) steps_out[row] = 16.f;
    const float* hr = h + (size_t)row * HID;
    float* th = tot_h + (size_t)row * HID;
#pragma unroll
    for (int q = 0; q < 4; q++) {
        int c = q * 256 + lane * 4;
        float4 hv = *(const float4*)(hr + c);
        float4 ov = *(const float4*)(th + c);
        ov.x += cmb * hv.x; ov.y += cmb * hv.y;
        ov.z += cmb * hv.z; ov.w += cmb * hv.w;
        *(float4*)(th + c) = ov;
    }
}

extern "C" void kernel_launch(void* const* d_in, const int* in_sizes, int n_in,
                              void* d_out, int out_size, void* d_ws, size_t ws_size,
                              hipStream_t stream) {
    const float* inputs = (const float*)d_in[0];
    const float* hidden = (const float*)d_in[1];
    const float* W_ih   = (const float*)d_in[2];
    const float* b_ih   = (const float*)d_in[3];
    const float* W_hh   = (const float*)d_in[4];
    const float* b_hh   = (const float*)d_in[5];
    const float* W_halt = (const float*)d_in[6];
    const float* b_halt = (const float*)d_in[7];
    float* out = (float*)d_out;

    float* ws = (float*)d_ws;
    float* xbase = ws;                                   // 4096*1024
    float* h0 = xbase + (size_t)BATCH * HID;             // 4096*1024
    float* h1 = h0 + (size_t)BATCH * HID;                // 4096*1024
    float* Wp = h1 + (size_t)BATCH * HID;                // 1024*1024 repacked W_ih
    float* flagcol = Wp + (size_t)KDIM * KDIM;           // 1024
    float* halt_accum = flagcol + KDIM;                  // 4096
    float* tot_rem = halt_accum + BATCH;                 // 4096
    int* list0 = (int*)(tot_rem + BATCH);                // 4096 ints
    int* list1 = list0 + BATCH;                          // 4096 ints
    int* counts = list1 + BATCH;                         // 16 ints

    float* hb[2] = {h0, h1};
    int* lists[2] = {list0, list1};

    float* tot_h = out;                                  // 4096*1024
    float* ponder = out + (size_t)BATCH * HID;           // 1
    float* steps_out = ponder + 1;                       // 4096

    setup_kernel<<<4096, 256, 0, stream>>>(W_ih, Wp, flagcol, list0, counts,
                                           halt_accum, tot_rem);

    // x_base = inputs @ W_ih[:, :-1].T + b_ih
    gemm_kernel<<<dim3(64, 8), 128, 0, stream>>>(inputs, Wp, b_ih, nullptr, nullptr, 0.f,
                                                 nullptr, nullptr, xbase, 0);
    for (int t = 0; t < NSTEP; t++) {
        const float* hprev = (t == 0) ? hidden : hb[(t - 1) & 1];
        gemm_kernel<<<dim3(64, 8), 128, 0, stream>>>(hprev, W_hh, b_hh, xbase, flagcol,
                                                     (t == 0) ? 1.f : 0.f,
                                                     lists[t & 1], counts + t, hb[t & 1], 1);
        halt_kernel<<<1024, 256, 0, stream>>>(hb[t & 1], W_halt, b_halt,
                                              lists[t & 1], counts + t,
                                              lists[(t + 1) & 1], counts + t + 1,
                                              halt_accum, tot_rem, tot_h, steps_out,
                                              t + 1, (t == 0) ? 1 : 0);
    }
    epilogue_kernel<<<1025, 256, 0, stream>>>(hb[0], lists[1], counts + 15,
                                              halt_accum, tot_rem, tot_h, steps_out, ponder);
}